// Round 20
// baseline (548.278 us; speedup 1.0000x reference)
//
#include <hip/hip_runtime.h>
#include <hip/hip_bf16.h>

// ---- static problem config ----
// B=32, H=W=64, C=256, WS=8, SHIFT=4, NH=8, HD=32, N=64 tok/window.
// R13 kernel set (best verified: 532.7us), launcher-only change:
// 2 chunks x 16 images (13 dispatches vs 25). Gc reuses dead XWc+QKVc region
// so every phase's active L3 set stays < 256MB.

typedef __bf16 bf16;
typedef __bf16 bf16x8 __attribute__((ext_vector_type(8)));
typedef __bf16 bf16x4 __attribute__((ext_vector_type(4)));
typedef float  f32x4  __attribute__((ext_vector_type(4)));

#define GLDS(gp, lp)                                                                   \
    __builtin_amdgcn_global_load_lds(                                                  \
        (const __attribute__((address_space(1))) unsigned int*)(gp),                   \
        (__attribute__((address_space(3))) unsigned int*)(lp), 16, 0, 0)

// ---------------- fused prep ----------------
__global__ __launch_bounds__(256) void prep_all(const float* __restrict__ qkv_w,
                                                const float* __restrict__ proj_w,
                                                const float* __restrict__ fc1_w,
                                                const float* __restrict__ fc2_w,
                                                const float* __restrict__ bt,
                                                bf16* __restrict__ WQ, bf16* __restrict__ WP,
                                                bf16* __restrict__ W1, bf16* __restrict__ W2,
                                                float* __restrict__ rpb) {
    int idx = blockIdx.x * 256 + threadIdx.x;  // 819200
    if (idx < 196608) {
        int k = idx / 768, n = idx - k * 768;
        WQ[(size_t)n * 256 + k] = (bf16)qkv_w[idx];
    } else if (idx < 262144) {
        int l = idx - 196608;
        int k = l >> 8, n = l & 255;
        WP[(size_t)n * 256 + k] = (bf16)proj_w[l];
    } else if (idx < 524288) {
        int l = idx - 262144;
        int k = l >> 10, n = l & 1023;
        W1[(size_t)n * 256 + k] = (bf16)fc1_w[l];
    } else if (idx < 786432) {
        int l = idx - 524288;
        int k = l >> 8, n = l & 255;
        W2[(size_t)n * 1024 + k] = (bf16)fc2_w[l];
    } else {
        int l = idx - 786432;
        int h = l >> 12, n = (l >> 6) & 63, m = l & 63;
        int ridx = ((n >> 3) - (m >> 3) + 7) * 15 + ((n & 7) - (m & 7) + 7);
        rpb[l] = bt[ridx * 8 + h];
    }
}

// ---------------- LayerNorm1 + shift + window partition ----------------
__global__ __launch_bounds__(256) void ln_k(const float* __restrict__ x,
                                            const float* __restrict__ g,
                                            const float* __restrict__ bb,
                                            bf16* __restrict__ dst) {
    int t = blockIdx.x * 4 + (threadIdx.x >> 6);
    int lane = threadIdx.x & 63;
    int w = t >> 6, n = t & 63;
    int b = w >> 6, nw = w & 63;
    int r = ((nw >> 3) * 8 + (n >> 3) + 4) & 63;
    int c = ((nw & 7) * 8 + (n & 7) + 4) & 63;
    size_t src = ((size_t)b * 4096 + r * 64 + c) * 256;
    float4 v = *(const float4*)&x[src + lane * 4];
    float s = v.x + v.y + v.z + v.w;
    float sq = v.x * v.x + v.y * v.y + v.z * v.z + v.w * v.w;
#pragma unroll
    for (int off = 1; off < 64; off <<= 1) {
        s += __shfl_xor(s, off);
        sq += __shfl_xor(sq, off);
    }
    float mean = s * (1.0f / 256.0f);
    float var = sq * (1.0f / 256.0f) - mean * mean;
    float rstd = rsqrtf(var + 1e-5f);
    float4 gg = *(const float4*)&g[lane * 4];
    float4 bv = *(const float4*)&bb[lane * 4];
    bf16x4 o;
    o[0] = (bf16)((v.x - mean) * rstd * gg.x + bv.x);
    o[1] = (bf16)((v.y - mean) * rstd * gg.y + bv.y);
    o[2] = (bf16)((v.z - mean) * rstd * gg.z + bv.z);
    o[3] = (bf16)((v.w - mean) * rstd * gg.w + bv.w);
    *(bf16x4*)&dst[(size_t)t * 256 + lane * 4] = o;
}

__device__ __forceinline__ float fast_gelu(float v) {
    float t = v * v;
    float w = __builtin_fmaf(0.044715f * t, v, v);
    float e = __expf(-1.5957691216057308f * w);
    return v * __builtin_amdgcn_rcpf(1.0f + e);
}

// ---------------- GEMM (R13 structure) ----------------
template <int NDIM, int KDIM, int EPI>
__global__ __launch_bounds__(256) void gemm_k(const bf16* __restrict__ A,
                                              const bf16* __restrict__ Bt,
                                              const float* __restrict__ bias,
                                              bf16* __restrict__ outb,
                                              float* __restrict__ outf,
                                              const bf16* __restrict__ baseb) {
    __shared__ __align__(16) bf16 SH[24576];  // 48KB
    constexpr int NBN = NDIM / 128;
    constexpr int NK = KDIM / 32;
    static_assert(NK >= 3, "pipeline needs >=3 K-steps");
    const int tid = threadIdx.x;
    const int nwg = gridDim.x;
    const int flat = blockIdx.x;
    const int cpx = nwg >> 3;
    const int orig = (flat & 7) * cpx + (flat >> 3);
    const int bm = orig / NBN, bn = orig % NBN;

    const int lane = tid & 63, wid = tid >> 6;
    const int wr = wid >> 1, wc = wid & 1;
    const int lhi = lane >> 4, llo = lane & 15;

    f32x4 acc[4][4];
#pragma unroll
    for (int i = 0; i < 4; i++)
#pragma unroll
        for (int j = 0; j < 4; j++) acc[i][j] = f32x4{0.f, 0.f, 0.f, 0.f};

    const int srow = wid * 32 + (lane >> 2);
    const int scol = (((lane & 3) - ((lane >> 3) & 3)) & 3) * 8;
    const bf16* Ap = A + (size_t)(bm * 128 + srow) * KDIM + scol;
    const bf16* Bp = Bt + (size_t)(bn * 128 + srow) * KDIM + scol;
    const int gsw = ((lhi + (llo >> 1)) & 3) * 8;

#define STAGE(bufidx)                                                                  \
    do {                                                                               \
        bf16* Al = SH + (bufidx)*4096 + wid * 1024;                                    \
        bf16* Bl = SH + 12288 + (bufidx)*4096 + wid * 1024;                            \
        GLDS(Ap, Al);                                                                  \
        GLDS(Ap + 16 * KDIM, Al + 16 * 32);                                            \
        GLDS(Bp, Bl);                                                                  \
        GLDS(Bp + 16 * KDIM, Bl + 16 * 32);                                            \
        Ap += 32;                                                                      \
        Bp += 32;                                                                      \
    } while (0)

#define COMPUTE(bufidx)                                                                \
    do {                                                                               \
        const int ab = (bufidx)*4096;                                                  \
        bf16x8 af[4], bfr[4];                                                          \
        _Pragma("unroll") for (int mi = 0; mi < 4; mi++) af[mi] =                      \
            *(const bf16x8*)&SH[ab + (wr * 64 + mi * 16 + llo) * 32 + gsw];            \
        _Pragma("unroll") for (int ni = 0; ni < 4; ni++) bfr[ni] =                     \
            *(const bf16x8*)&SH[12288 + ab + (wc * 64 + ni * 16 + llo) * 32 + gsw];    \
        _Pragma("unroll") for (int mi = 0; mi < 4; mi++)                               \
            _Pragma("unroll") for (int ni = 0; ni < 4; ni++) acc[mi][ni] =             \
                __builtin_amdgcn_mfma_f32_16x16x32_bf16(bfr[ni], af[mi],               \
                                                        acc[mi][ni], 0, 0, 0);         \
    } while (0)

#define WAITBAR(N)                                                                     \
    asm volatile("s_waitcnt vmcnt(" #N ")" ::: "memory");                              \
    __builtin_amdgcn_s_barrier();                                                      \
    __builtin_amdgcn_sched_barrier(0)

#define END_PHASE                                                                      \
    asm volatile("s_waitcnt lgkmcnt(0)" ::: "memory");                                 \
    __builtin_amdgcn_s_barrier();                                                      \
    __builtin_amdgcn_sched_barrier(0)

    STAGE(0);
    STAGE(1);
    STAGE(2);
    int buf = 0;
    for (int i = 0; i + 3 < NK; ++i) {
        WAITBAR(8);
        COMPUTE(buf);
        END_PHASE;
        STAGE(buf);
        buf = (buf == 2) ? 0 : buf + 1;
    }
    WAITBAR(8);
    COMPUTE(buf);
    buf = (buf == 2) ? 0 : buf + 1;
    WAITBAR(4);
    COMPUTE(buf);
    buf = (buf == 2) ? 0 : buf + 1;
    WAITBAR(0);
    COMPUTE(buf);

#undef STAGE
#undef COMPUTE
#undef WAITBAR
#undef END_PHASE

    __syncthreads();

    char* shb = (char*)SH;
    if constexpr (EPI == 0 || EPI == 2) {
#pragma unroll
        for (int ni = 0; ni < 4; ni++) {
            const int lcol = wc * 64 + ni * 16 + lhi * 4;
            const float4 b4 = *(const float4*)&bias[bn * 128 + lcol];
#pragma unroll
            for (int mi = 0; mi < 4; mi++) {
                const int ltok = wr * 64 + mi * 16 + llo;
                float v0 = acc[mi][ni][0] + b4.x;
                float v1 = acc[mi][ni][1] + b4.y;
                float v2 = acc[mi][ni][2] + b4.z;
                float v3 = acc[mi][ni][3] + b4.w;
                bf16x4 o;
                if constexpr (EPI == 2) {
                    o[0] = (bf16)fast_gelu(v0); o[1] = (bf16)fast_gelu(v1);
                    o[2] = (bf16)fast_gelu(v2); o[3] = (bf16)fast_gelu(v3);
                } else {
                    o[0] = (bf16)v0; o[1] = (bf16)v1; o[2] = (bf16)v2; o[3] = (bf16)v3;
                }
                const int u2 = (lcol >> 3) ^ (ltok & 15);
                *(bf16x4*)(shb + ltok * 256 + u2 * 16 + (lcol & 7) * 2) = o;
            }
        }
        __syncthreads();
        const int j = lane & 15;
#pragma unroll
        for (int rnd = 0; rnd < 8; rnd++) {
            const int ltok = wid * 32 + rnd * 4 + (lane >> 4);
            const int u2 = j ^ (ltok & 15);
            bf16x8 v = *(const bf16x8*)(shb + ltok * 256 + u2 * 16);
            *(bf16x8*)&outb[(size_t)(bm * 128 + ltok) * NDIM + bn * 128 + j * 8] = v;
        }
    } else {
#pragma unroll
        for (int p = 0; p < 2; p++) {
            if (wc == p) {
#pragma unroll
                for (int ni = 0; ni < 4; ni++) {
                    const int lcolh = ni * 16 + lhi * 4;
                    const float4 b4 = *(const float4*)&bias[bn * 128 + p * 64 + lcolh];
#pragma unroll
                    for (int mi = 0; mi < 4; mi++) {
                        const int ltok = wr * 64 + mi * 16 + llo;
                        float4 o = {acc[mi][ni][0] + b4.x, acc[mi][ni][1] + b4.y,
                                    acc[mi][ni][2] + b4.z, acc[mi][ni][3] + b4.w};
                        const int u2 = (lcolh >> 2) ^ (ltok & 15);
                        *(float4*)(shb + ltok * 256 + u2 * 16) = o;
                    }
                }
            }
            __syncthreads();
            const int j = lane & 15;
#pragma unroll
            for (int rnd = 0; rnd < 8; rnd++) {
                const int ltok = wid * 32 + rnd * 4 + (lane >> 4);
                const int u2 = j ^ (ltok & 15);
                float4 v = *(const float4*)(shb + ltok * 256 + u2 * 16);
                const int gcol = bn * 128 + p * 64 + j * 4;
                const int grow = bm * 128 + ltok;
                size_t dst = (size_t)grow * NDIM + gcol;
                bf16x4 bb = *(const bf16x4*)&baseb[dst];
                float4 o = {v.x + (float)bb[0], v.y + (float)bb[1],
                            v.z + (float)bb[2], v.w + (float)bb[3]};
                *(float4*)&outf[dst] = o;
            }
            if (p == 0) __syncthreads();
        }
    }
}

// ------- proj + residual + window-reverse/unshift + LN2 fused (R13) -------
__global__ __launch_bounds__(256) void proj_ln_k(const bf16* __restrict__ A,
                                                 const bf16* __restrict__ Bt,
                                                 const float* __restrict__ bias,
                                                 const float* __restrict__ resid,
                                                 bf16* __restrict__ baseb,
                                                 const float* __restrict__ g2,
                                                 const float* __restrict__ b2,
                                                 bf16* __restrict__ hb) {
    __shared__ __align__(16) bf16 SH[32768];  // 64KB
    constexpr int KDIM = 256;
    const int tid = threadIdx.x;
    const int nwg = gridDim.x;  // %8==0
    const int flat = blockIdx.x;
    const int cpx = nwg >> 3;
    const int bm = (flat & 7) * cpx + (flat >> 3);

    const int lane = tid & 63, wid = tid >> 6;
    const int lhi = lane >> 4, llo = lane & 15;

    f32x4 acc[4][4];
#pragma unroll
    for (int i = 0; i < 4; i++)
#pragma unroll
        for (int j = 0; j < 4; j++) acc[i][j] = f32x4{0.f, 0.f, 0.f, 0.f};

    const int scol = (((lane & 3) - ((lane >> 3) & 3)) & 3) * 8;
    const bf16* Ap = A + (size_t)(bm * 64 + wid * 16 + (lane >> 2)) * KDIM + scol;
    const bf16* Bp = Bt + (size_t)(wid * 64 + (lane >> 2)) * KDIM + scol;
    const int gsw = ((lhi + (llo >> 1)) & 3) * 8;

#define PSTAGE(bufidx)                                                                 \
    do {                                                                               \
        bf16* Al = SH + (bufidx)*2048 + wid * 512;                                     \
        bf16* Bl = SH + 6144 + (bufidx)*8192 + wid * 2048;                             \
        GLDS(Ap, Al);                                                                  \
        GLDS(Bp, Bl);                                                                  \
        GLDS(Bp + 16 * KDIM, Bl + 512);                                                \
        GLDS(Bp + 32 * KDIM, Bl + 1024);                                               \
        GLDS(Bp + 48 * KDIM, Bl + 1536);                                               \
        Ap += 32;                                                                      \
        Bp += 32;                                                                      \
    } while (0)

#define PCOMPUTE(bufidx)                                                               \
    do {                                                                               \
        bf16x8 af[4], bfr[4];                                                          \
        _Pragma("unroll") for (int mi = 0; mi < 4; mi++) af[mi] =                      \
            *(const bf16x8*)&SH[(bufidx)*2048 + (mi * 16 + llo) * 32 + gsw];           \
        _Pragma("unroll") for (int ni = 0; ni < 4; ni++) bfr[ni] =                     \
            *(const bf16x8*)&SH[6144 + (bufidx)*8192 +                                 \
                                (wid * 64 + ni * 16 + llo) * 32 + gsw];                \
        _Pragma("unroll") for (int mi = 0; mi < 4; mi++)                               \
            _Pragma("unroll") for (int ni = 0; ni < 4; ni++) acc[mi][ni] =             \
                __builtin_amdgcn_mfma_f32_16x16x32_bf16(bfr[ni], af[mi],               \
                                                        acc[mi][ni], 0, 0, 0);         \
    } while (0)

#define PWAITBAR(N)                                                                    \
    asm volatile("s_waitcnt vmcnt(" #N ")" ::: "memory");                              \
    __builtin_amdgcn_s_barrier();                                                      \
    __builtin_amdgcn_sched_barrier(0)

    PSTAGE(0);
    PSTAGE(1);
    PSTAGE(2);
    int buf = 0;
    for (int i = 0; i + 3 < 8; ++i) {
        PWAITBAR(10);
        PCOMPUTE(buf);
        asm volatile("s_waitcnt lgkmcnt(0)" ::: "memory");
        __builtin_amdgcn_s_barrier();
        __builtin_amdgcn_sched_barrier(0);
        PSTAGE(buf);
        buf = (buf == 2) ? 0 : buf + 1;
    }
    PWAITBAR(10);
    PCOMPUTE(buf);
    buf = (buf == 2) ? 0 : buf + 1;
    PWAITBAR(5);
    PCOMPUTE(buf);
    buf = (buf == 2) ? 0 : buf + 1;
    PWAITBAR(0);
    PCOMPUTE(buf);

#undef PSTAGE
#undef PCOMPUTE
#undef PWAITBAR

    __syncthreads();

    char* shb = (char*)SH;
#pragma unroll
    for (int ni = 0; ni < 4; ni++) {
        const int col0 = wid * 64 + ni * 16 + lhi * 4;
        const float4 b4 = *(const float4*)&bias[col0];
#pragma unroll
        for (int mi = 0; mi < 4; mi++) {
            const int ltok = mi * 16 + llo;
            float4 o = {acc[mi][ni][0] + b4.x, acc[mi][ni][1] + b4.y,
                        acc[mi][ni][2] + b4.z, acc[mi][ni][3] + b4.w};
            const int u2 = (col0 >> 2) ^ (ltok & 15);
            *(float4*)(shb + ltok * 1024 + u2 * 16) = o;
        }
    }
    __syncthreads();

    const float4 gg = *(const float4*)&g2[lane * 4];
    const float4 bb4 = *(const float4*)&b2[lane * 4];
#pragma unroll
    for (int rnd = 0; rnd < 16; rnd++) {
        const int t = rnd * 4 + wid;
        const int u2 = lane ^ (t & 15);
        float4 v = *(const float4*)(shb + t * 1024 + u2 * 16);
        const int grow = bm * 64 + t;
        int w = grow >> 6, n = grow & 63;
        int b = w >> 6, nw = w & 63;
        int rr = ((nw >> 3) * 8 + (n >> 3) + 4) & 63;
        int cc = ((nw & 7) * 8 + (n & 7) + 4) & 63;
        const size_t rowbase = ((size_t)b * 4096 + rr * 64 + cc) * 256;
        float4 rs = *(const float4*)&resid[rowbase + lane * 4];
        float4 o = {rs.x + v.x, rs.y + v.y, rs.z + v.z, rs.w + v.w};
        bf16x4 bo = {(bf16)o.x, (bf16)o.y, (bf16)o.z, (bf16)o.w};
        *(bf16x4*)&baseb[rowbase + lane * 4] = bo;
        float s = o.x + o.y + o.z + o.w;
        float sq = o.x * o.x + o.y * o.y + o.z * o.z + o.w * o.w;
#pragma unroll
        for (int off = 1; off < 64; off <<= 1) {
            s += __shfl_xor(s, off);
            sq += __shfl_xor(sq, off);
        }
        float mean = s * (1.0f / 256.0f);
        float var = sq * (1.0f / 256.0f) - mean * mean;
        float rstd = rsqrtf(var + 1e-5f);
        bf16x4 ho;
        ho[0] = (bf16)((o.x - mean) * rstd * gg.x + bb4.x);
        ho[1] = (bf16)((o.y - mean) * rstd * gg.y + bb4.y);
        ho[2] = (bf16)((o.z - mean) * rstd * gg.z + bb4.z);
        ho[3] = (bf16)((o.w - mean) * rstd * gg.w + bb4.w);
        *(bf16x4*)&hb[rowbase + lane * 4] = ho;
    }
}

// ---------------- windowed attention ----------------
__device__ __forceinline__ int regid3(int p) { return p < 56 ? 0 : (p < 60 ? 1 : 2); }

__global__ __launch_bounds__(256) void attn_k(const bf16* __restrict__ qkv,
                                              const float* __restrict__ rpb,
                                              bf16* __restrict__ aout) {
    __shared__ __align__(16) bf16 Pl[4][64 * 80];
    const int wid = threadIdx.x >> 6, lane = threadIdx.x & 63;
    const int lhi = lane >> 4, llo = lane & 15;
    const int wh = blockIdx.x * 4 + wid;
    const int w = wh >> 3, h = wh & 7;
    const bf16* base = qkv + (size_t)w * (64 * 768);

    bf16x8 qf[4], kf[4];
#pragma unroll
    for (int i = 0; i < 4; i++)
        qf[i] = *(const bf16x8*)(base + (i * 16 + llo) * 768 + h * 32 + lhi * 8);
#pragma unroll
    for (int i = 0; i < 4; i++)
        kf[i] = *(const bf16x8*)(base + (i * 16 + llo) * 768 + 256 + h * 32 + lhi * 8);
    f32x4 s[4][4];
#pragma unroll
    for (int mi = 0; mi < 4; mi++)
#pragma unroll
        for (int ni = 0; ni < 4; ni++) {
            s[mi][ni] = f32x4{0.f, 0.f, 0.f, 0.f};
            s[mi][ni] =
                __builtin_amdgcn_mfma_f32_16x16x32_bf16(qf[mi], kf[ni], s[mi][ni], 0, 0, 0);
        }

    const int nw = w & 63;
    const int pr0 = (nw >> 3) * 8, pc0 = (nw & 7) * 8;
    int creg[4];
#pragma unroll
    for (int ni = 0; ni < 4; ni++) {
        int m = ni * 16 + llo;
        creg[ni] = regid3(pr0 + (m >> 3)) * 3 + regid3(pc0 + (m & 7));
    }
    float rmax[4][4], rsum[4][4];
#pragma unroll
    for (int mi = 0; mi < 4; mi++)
#pragma unroll
        for (int r = 0; r < 4; r++) {
            int n = mi * 16 + lhi * 4 + r;
            int rreg = regid3(pr0 + (n >> 3)) * 3 + regid3(pc0 + (n & 7));
            float mx = -1e30f;
#pragma unroll
            for (int ni = 0; ni < 4; ni++) {
                int m = ni * 16 + llo;
                float sv = s[mi][ni][r] * 0.17677669529663687f + rpb[(h * 64 + n) * 64 + m] +
                           (rreg == creg[ni] ? 0.0f : -100.0f);
                s[mi][ni][r] = sv;
                mx = fmaxf(mx, sv);
            }
            rmax[mi][r] = mx;
        }
#pragma unroll
    for (int off = 1; off < 16; off <<= 1)
#pragma unroll
        for (int mi = 0; mi < 4; mi++)
#pragma unroll
            for (int r = 0; r < 4; r++)
                rmax[mi][r] = fmaxf(rmax[mi][r], __shfl_xor(rmax[mi][r], off));
#pragma unroll
    for (int mi = 0; mi < 4; mi++)
#pragma unroll
        for (int r = 0; r < 4; r++) {
            float a = 0.f;
#pragma unroll
            for (int ni = 0; ni < 4; ni++) {
                float p = __expf(s[mi][ni][r] - rmax[mi][r]);
                s[mi][ni][r] = p;
                a += p;
            }
            rsum[mi][r] = a;
        }
#pragma unroll
    for (int off = 1; off < 16; off <<= 1)
#pragma unroll
        for (int mi = 0; mi < 4; mi++)
#pragma unroll
            for (int r = 0; r < 4; r++) rsum[mi][r] += __shfl_xor(rsum[mi][r], off);

    bf16* P = Pl[wid];
#pragma unroll
    for (int mi = 0; mi < 4; mi++)
#pragma unroll
        for (int r = 0; r < 4; r++) {
            float rinv = 1.0f / rsum[mi][r];
            int row = mi * 16 + lhi * 4 + r;
#pragma unroll
            for (int ni = 0; ni < 4; ni++)
                P[row * 80 + ni * 16 + llo] = (bf16)(s[mi][ni][r] * rinv);
        }

    f32x4 o[4][2];
#pragma unroll
    for (int mi = 0; mi < 4; mi++)
#pragma unroll
        for (int ni = 0; ni < 2; ni++) o[mi][ni] = f32x4{0.f, 0.f, 0.f, 0.f};
#pragma unroll
    for (int kc = 0; kc < 2; kc++) {
        bf16x8 pf[4], vf[2];
#pragma unroll
        for (int mi = 0; mi < 4; mi++)
            pf[mi] = *(const bf16x8*)(P + (mi * 16 + llo) * 80 + kc * 32 + lhi * 8);
#pragma unroll
        for (int ni = 0; ni < 2; ni++)
#pragma unroll
            for (int j = 0; j < 8; j++)
                vf[ni][j] = base[(kc * 32 + lhi * 8 + j) * 768 + 512 + h * 32 + ni * 16 + llo];
#pragma unroll
        for (int mi = 0; mi < 4; mi++)
#pragma unroll
            for (int ni = 0; ni < 2; ni++)
                o[mi][ni] =
                    __builtin_amdgcn_mfma_f32_16x16x32_bf16(pf[mi], vf[ni], o[mi][ni], 0, 0, 0);
    }
#pragma unroll
    for (int mi = 0; mi < 4; mi++)
#pragma unroll
        for (int ni = 0; ni < 2; ni++)
#pragma unroll
            for (int r = 0; r < 4; r++) {
                int row = mi * 16 + lhi * 4 + r;
                aout[(size_t)(w * 64 + row) * 256 + h * 32 + ni * 16 + llo] =
                    (bf16)o[mi][ni][r];
            }
}

// ---------------- launcher: 2 chunks x 16 images ----------------
// ws layout (MB): XWc@0(34) | QKVc@34(101) -> Gc@0(135) reuses both after attn
// | ATTNc@135(34) | BASEc@169(34) | Hbc@203(34) | weights@238.
extern "C" void kernel_launch(void* const* d_in, const int* in_sizes, int n_in,
                              void* d_out, int out_size, void* d_ws, size_t ws_size,
                              hipStream_t stream) {
    const float* x      = (const float*)d_in[0];
    const float* n1g    = (const float*)d_in[1];
    const float* n1b    = (const float*)d_in[2];
    const float* qkv_w  = (const float*)d_in[3];
    const float* qkv_b  = (const float*)d_in[4];
    const float* proj_w = (const float*)d_in[5];
    const float* proj_b = (const float*)d_in[6];
    const float* btab   = (const float*)d_in[7];
    const float* n2g    = (const float*)d_in[8];
    const float* n2b    = (const float*)d_in[9];
    const float* fc1_w  = (const float*)d_in[10];
    const float* fc1_b  = (const float*)d_in[11];
    const float* fc2_w  = (const float*)d_in[12];
    const float* fc2_b  = (const float*)d_in[13];
    float* out = (float*)d_out;
    char* ws = (char*)d_ws;

    constexpr size_t MB = 1048576ull;
    bf16* XWc   = (bf16*)(ws);               // 33.6MB (dead after QKV)
    bf16* QKVc  = (bf16*)(ws + 34 * MB);     // 100.7MB (dead after attn)
    bf16* Gc    = (bf16*)(ws);               // 134.2MB, reuses XWc+QKVc region
    bf16* ATTNc = (bf16*)(ws + 135 * MB);    // 33.6MB
    bf16* BASEc = (bf16*)(ws + 169 * MB);    // 33.6MB
    bf16* Hbc   = (bf16*)(ws + 203 * MB);    // 33.6MB
    bf16* WQ    = (bf16*)(ws + 238 * MB);
    bf16* WP    = (bf16*)(ws + 238 * MB + 393216);
    bf16* W1    = (bf16*)(ws + 238 * MB + 524288);
    bf16* W2    = (bf16*)(ws + 238 * MB + 1048576);
    float* RPB  = (float*)(ws + 238 * MB + 1572864);

    dim3 blk(256);
    prep_all<<<3200, blk, 0, stream>>>(qkv_w, proj_w, fc1_w, fc2_w, btab,
                                       WQ, WP, W1, W2, RPB);

    for (int c = 0; c < 2; ++c) {
        const size_t xo = (size_t)c * 65536 * 256;
        // LN1 + shift + partition (chunk-local)
        ln_k<<<16384, blk, 0, stream>>>(x + xo, n1g, n1b, XWc);
        // QKV
        gemm_k<768, 256, 0><<<3072, blk, 0, stream>>>(XWc, WQ, qkv_b, QKVc,
                                                      nullptr, nullptr);
        // attention (1024 windows x 8 heads / 4 waves)
        attn_k<<<2048, blk, 0, stream>>>(QKVc, RPB, ATTNc);
        // proj + residual + reverse/unshift + LN2 -> baseb, Hb
        proj_ln_k<<<1024, blk, 0, stream>>>(ATTNc, WP, proj_b, x + xo, BASEc,
                                            n2g, n2b, Hbc);
        // FC1 + GELU  (Gc overwrites dead XWc/QKVc)
        gemm_k<1024, 256, 2><<<4096, blk, 0, stream>>>(Hbc, W1, fc1_b, Gc,
                                                       nullptr, nullptr);
        // FC2 + bias + base -> out (single write)
        gemm_k<256, 1024, 3><<<1024, blk, 0, stream>>>(Gc, W2, fc2_b, nullptr,
                                                       out + xo, BASEc);
    }
}

// Round 21
// 531.875 us; speedup vs baseline: 1.0308x; 1.0308x over previous
//
#include <hip/hip_runtime.h>
#include <hip/hip_bf16.h>

// ---- static problem config ----
// B=32, H=W=64, C=256, WS=8, SHIFT=4, NH=8, HD=32, N=64 tok/window.
// FINAL: R13 configuration (verified 532.7/533.5/534.5us): 4-chunk L3
// pipeline, 128x128 3-buffer GEMM, fused proj+LN2, bf16 base, single-write FC2.

typedef __bf16 bf16;
typedef __bf16 bf16x8 __attribute__((ext_vector_type(8)));
typedef __bf16 bf16x4 __attribute__((ext_vector_type(4)));
typedef float  f32x4  __attribute__((ext_vector_type(4)));

#define GLDS(gp, lp)                                                                   \
    __builtin_amdgcn_global_load_lds(                                                  \
        (const __attribute__((address_space(1))) unsigned int*)(gp),                   \
        (__attribute__((address_space(3))) unsigned int*)(lp), 16, 0, 0)

// ---------------- fused prep ----------------
__global__ __launch_bounds__(256) void prep_all(const float* __restrict__ qkv_w,
                                                const float* __restrict__ proj_w,
                                                const float* __restrict__ fc1_w,
                                                const float* __restrict__ fc2_w,
                                                const float* __restrict__ bt,
                                                bf16* __restrict__ WQ, bf16* __restrict__ WP,
                                                bf16* __restrict__ W1, bf16* __restrict__ W2,
                                                float* __restrict__ rpb) {
    int idx = blockIdx.x * 256 + threadIdx.x;  // 819200
    if (idx < 196608) {
        int k = idx / 768, n = idx - k * 768;
        WQ[(size_t)n * 256 + k] = (bf16)qkv_w[idx];
    } else if (idx < 262144) {
        int l = idx - 196608;
        int k = l >> 8, n = l & 255;
        WP[(size_t)n * 256 + k] = (bf16)proj_w[l];
    } else if (idx < 524288) {
        int l = idx - 262144;
        int k = l >> 10, n = l & 1023;
        W1[(size_t)n * 256 + k] = (bf16)fc1_w[l];
    } else if (idx < 786432) {
        int l = idx - 524288;
        int k = l >> 8, n = l & 255;
        W2[(size_t)n * 1024 + k] = (bf16)fc2_w[l];
    } else {
        int l = idx - 786432;
        int h = l >> 12, n = (l >> 6) & 63, m = l & 63;
        int ridx = ((n >> 3) - (m >> 3) + 7) * 15 + ((n & 7) - (m & 7) + 7);
        rpb[l] = bt[ridx * 8 + h];
    }
}

// ---------------- LayerNorm1 + shift + window partition ----------------
__global__ __launch_bounds__(256) void ln_k(const float* __restrict__ x,
                                            const float* __restrict__ g,
                                            const float* __restrict__ bb,
                                            bf16* __restrict__ dst) {
    int t = blockIdx.x * 4 + (threadIdx.x >> 6);
    int lane = threadIdx.x & 63;
    int w = t >> 6, n = t & 63;
    int b = w >> 6, nw = w & 63;
    int r = ((nw >> 3) * 8 + (n >> 3) + 4) & 63;
    int c = ((nw & 7) * 8 + (n & 7) + 4) & 63;
    size_t src = ((size_t)b * 4096 + r * 64 + c) * 256;
    float4 v = *(const float4*)&x[src + lane * 4];
    float s = v.x + v.y + v.z + v.w;
    float sq = v.x * v.x + v.y * v.y + v.z * v.z + v.w * v.w;
#pragma unroll
    for (int off = 1; off < 64; off <<= 1) {
        s += __shfl_xor(s, off);
        sq += __shfl_xor(sq, off);
    }
    float mean = s * (1.0f / 256.0f);
    float var = sq * (1.0f / 256.0f) - mean * mean;
    float rstd = rsqrtf(var + 1e-5f);
    float4 gg = *(const float4*)&g[lane * 4];
    float4 bv = *(const float4*)&bb[lane * 4];
    bf16x4 o;
    o[0] = (bf16)((v.x - mean) * rstd * gg.x + bv.x);
    o[1] = (bf16)((v.y - mean) * rstd * gg.y + bv.y);
    o[2] = (bf16)((v.z - mean) * rstd * gg.z + bv.z);
    o[3] = (bf16)((v.w - mean) * rstd * gg.w + bv.w);
    *(bf16x4*)&dst[(size_t)t * 256 + lane * 4] = o;
}

__device__ __forceinline__ float fast_gelu(float v) {
    float t = v * v;
    float w = __builtin_fmaf(0.044715f * t, v, v);
    float e = __expf(-1.5957691216057308f * w);
    return v * __builtin_amdgcn_rcpf(1.0f + e);
}

// ---------------- GEMM (R13 structure) ----------------
// 128x128, BK=32, 4 waves, 3-deep LDS pipeline (48KB), global_load_lds w=16,
// counted vmcnt; swapped mfma(bfr, af); LDS-transpose epilogue.
// EPI 0: +bias -> bf16          [QKV]
// EPI 2: +bias, GELU -> bf16    [fc1]
// EPI 3: +bias + baseb(bf16) -> f32 out, single write  [fc2]
template <int NDIM, int KDIM, int EPI>
__global__ __launch_bounds__(256) void gemm_k(const bf16* __restrict__ A,
                                              const bf16* __restrict__ Bt,
                                              const float* __restrict__ bias,
                                              bf16* __restrict__ outb,
                                              float* __restrict__ outf,
                                              const bf16* __restrict__ baseb) {
    __shared__ __align__(16) bf16 SH[24576];  // 48KB
    constexpr int NBN = NDIM / 128;
    constexpr int NK = KDIM / 32;
    static_assert(NK >= 3, "pipeline needs >=3 K-steps");
    const int tid = threadIdx.x;
    const int nwg = gridDim.x;
    const int flat = blockIdx.x;
    const int cpx = nwg >> 3;
    const int orig = (flat & 7) * cpx + (flat >> 3);
    const int bm = orig / NBN, bn = orig % NBN;

    const int lane = tid & 63, wid = tid >> 6;
    const int wr = wid >> 1, wc = wid & 1;
    const int lhi = lane >> 4, llo = lane & 15;

    f32x4 acc[4][4];
#pragma unroll
    for (int i = 0; i < 4; i++)
#pragma unroll
        for (int j = 0; j < 4; j++) acc[i][j] = f32x4{0.f, 0.f, 0.f, 0.f};

    const int srow = wid * 32 + (lane >> 2);
    const int scol = (((lane & 3) - ((lane >> 3) & 3)) & 3) * 8;
    const bf16* Ap = A + (size_t)(bm * 128 + srow) * KDIM + scol;
    const bf16* Bp = Bt + (size_t)(bn * 128 + srow) * KDIM + scol;
    const int gsw = ((lhi + (llo >> 1)) & 3) * 8;

#define STAGE(bufidx)                                                                  \
    do {                                                                               \
        bf16* Al = SH + (bufidx)*4096 + wid * 1024;                                    \
        bf16* Bl = SH + 12288 + (bufidx)*4096 + wid * 1024;                            \
        GLDS(Ap, Al);                                                                  \
        GLDS(Ap + 16 * KDIM, Al + 16 * 32);                                            \
        GLDS(Bp, Bl);                                                                  \
        GLDS(Bp + 16 * KDIM, Bl + 16 * 32);                                            \
        Ap += 32;                                                                      \
        Bp += 32;                                                                      \
    } while (0)

#define COMPUTE(bufidx)                                                                \
    do {                                                                               \
        const int ab = (bufidx)*4096;                                                  \
        bf16x8 af[4], bfr[4];                                                          \
        _Pragma("unroll") for (int mi = 0; mi < 4; mi++) af[mi] =                      \
            *(const bf16x8*)&SH[ab + (wr * 64 + mi * 16 + llo) * 32 + gsw];            \
        _Pragma("unroll") for (int ni = 0; ni < 4; ni++) bfr[ni] =                     \
            *(const bf16x8*)&SH[12288 + ab + (wc * 64 + ni * 16 + llo) * 32 + gsw];    \
        _Pragma("unroll") for (int mi = 0; mi < 4; mi++)                               \
            _Pragma("unroll") for (int ni = 0; ni < 4; ni++) acc[mi][ni] =             \
                __builtin_amdgcn_mfma_f32_16x16x32_bf16(bfr[ni], af[mi],               \
                                                        acc[mi][ni], 0, 0, 0);         \
    } while (0)

#define WAITBAR(N)                                                                     \
    asm volatile("s_waitcnt vmcnt(" #N ")" ::: "memory");                              \
    __builtin_amdgcn_s_barrier();                                                      \
    __builtin_amdgcn_sched_barrier(0)

#define END_PHASE                                                                      \
    asm volatile("s_waitcnt lgkmcnt(0)" ::: "memory");                                 \
    __builtin_amdgcn_s_barrier();                                                      \
    __builtin_amdgcn_sched_barrier(0)

    STAGE(0);
    STAGE(1);
    STAGE(2);
    int buf = 0;
    for (int i = 0; i + 3 < NK; ++i) {
        WAITBAR(8);
        COMPUTE(buf);
        END_PHASE;
        STAGE(buf);
        buf = (buf == 2) ? 0 : buf + 1;
    }
    WAITBAR(8);
    COMPUTE(buf);
    buf = (buf == 2) ? 0 : buf + 1;
    WAITBAR(4);
    COMPUTE(buf);
    buf = (buf == 2) ? 0 : buf + 1;
    WAITBAR(0);
    COMPUTE(buf);

#undef STAGE
#undef COMPUTE
#undef WAITBAR
#undef END_PHASE

    __syncthreads();

    char* shb = (char*)SH;
    if constexpr (EPI == 0 || EPI == 2) {
#pragma unroll
        for (int ni = 0; ni < 4; ni++) {
            const int lcol = wc * 64 + ni * 16 + lhi * 4;
            const float4 b4 = *(const float4*)&bias[bn * 128 + lcol];
#pragma unroll
            for (int mi = 0; mi < 4; mi++) {
                const int ltok = wr * 64 + mi * 16 + llo;
                float v0 = acc[mi][ni][0] + b4.x;
                float v1 = acc[mi][ni][1] + b4.y;
                float v2 = acc[mi][ni][2] + b4.z;
                float v3 = acc[mi][ni][3] + b4.w;
                bf16x4 o;
                if constexpr (EPI == 2) {
                    o[0] = (bf16)fast_gelu(v0); o[1] = (bf16)fast_gelu(v1);
                    o[2] = (bf16)fast_gelu(v2); o[3] = (bf16)fast_gelu(v3);
                } else {
                    o[0] = (bf16)v0; o[1] = (bf16)v1; o[2] = (bf16)v2; o[3] = (bf16)v3;
                }
                const int u2 = (lcol >> 3) ^ (ltok & 15);
                *(bf16x4*)(shb + ltok * 256 + u2 * 16 + (lcol & 7) * 2) = o;
            }
        }
        __syncthreads();
        const int j = lane & 15;
#pragma unroll
        for (int rnd = 0; rnd < 8; rnd++) {
            const int ltok = wid * 32 + rnd * 4 + (lane >> 4);
            const int u2 = j ^ (ltok & 15);
            bf16x8 v = *(const bf16x8*)(shb + ltok * 256 + u2 * 16);
            *(bf16x8*)&outb[(size_t)(bm * 128 + ltok) * NDIM + bn * 128 + j * 8] = v;
        }
    } else {
        // ---- EPI 3: out = baseb + v, two 128x64 half-tiles, single write ----
#pragma unroll
        for (int p = 0; p < 2; p++) {
            if (wc == p) {
#pragma unroll
                for (int ni = 0; ni < 4; ni++) {
                    const int lcolh = ni * 16 + lhi * 4;
                    const float4 b4 = *(const float4*)&bias[bn * 128 + p * 64 + lcolh];
#pragma unroll
                    for (int mi = 0; mi < 4; mi++) {
                        const int ltok = wr * 64 + mi * 16 + llo;
                        float4 o = {acc[mi][ni][0] + b4.x, acc[mi][ni][1] + b4.y,
                                    acc[mi][ni][2] + b4.z, acc[mi][ni][3] + b4.w};
                        const int u2 = (lcolh >> 2) ^ (ltok & 15);
                        *(float4*)(shb + ltok * 256 + u2 * 16) = o;
                    }
                }
            }
            __syncthreads();
            const int j = lane & 15;
#pragma unroll
            for (int rnd = 0; rnd < 8; rnd++) {
                const int ltok = wid * 32 + rnd * 4 + (lane >> 4);
                const int u2 = j ^ (ltok & 15);
                float4 v = *(const float4*)(shb + ltok * 256 + u2 * 16);
                const int gcol = bn * 128 + p * 64 + j * 4;
                const int grow = bm * 128 + ltok;
                size_t dst = (size_t)grow * NDIM + gcol;
                bf16x4 bb = *(const bf16x4*)&baseb[dst];
                float4 o = {v.x + (float)bb[0], v.y + (float)bb[1],
                            v.z + (float)bb[2], v.w + (float)bb[3]};
                *(float4*)&outf[dst] = o;
            }
            if (p == 0) __syncthreads();
        }
    }
}

// ------- proj + residual + window-reverse/unshift + LN2 fused (R13) -------
__global__ __launch_bounds__(256) void proj_ln_k(const bf16* __restrict__ A,
                                                 const bf16* __restrict__ Bt,
                                                 const float* __restrict__ bias,
                                                 const float* __restrict__ resid,
                                                 bf16* __restrict__ baseb,
                                                 const float* __restrict__ g2,
                                                 const float* __restrict__ b2,
                                                 bf16* __restrict__ hb) {
    __shared__ __align__(16) bf16 SH[32768];  // 64KB
    constexpr int KDIM = 256;
    const int tid = threadIdx.x;
    const int nwg = gridDim.x;  // %8==0
    const int flat = blockIdx.x;
    const int cpx = nwg >> 3;
    const int bm = (flat & 7) * cpx + (flat >> 3);

    const int lane = tid & 63, wid = tid >> 6;
    const int lhi = lane >> 4, llo = lane & 15;

    f32x4 acc[4][4];
#pragma unroll
    for (int i = 0; i < 4; i++)
#pragma unroll
        for (int j = 0; j < 4; j++) acc[i][j] = f32x4{0.f, 0.f, 0.f, 0.f};

    const int scol = (((lane & 3) - ((lane >> 3) & 3)) & 3) * 8;
    const bf16* Ap = A + (size_t)(bm * 64 + wid * 16 + (lane >> 2)) * KDIM + scol;
    const bf16* Bp = Bt + (size_t)(wid * 64 + (lane >> 2)) * KDIM + scol;
    const int gsw = ((lhi + (llo >> 1)) & 3) * 8;

#define PSTAGE(bufidx)                                                                 \
    do {                                                                               \
        bf16* Al = SH + (bufidx)*2048 + wid * 512;                                     \
        bf16* Bl = SH + 6144 + (bufidx)*8192 + wid * 2048;                             \
        GLDS(Ap, Al);                                                                  \
        GLDS(Bp, Bl);                                                                  \
        GLDS(Bp + 16 * KDIM, Bl + 512);                                                \
        GLDS(Bp + 32 * KDIM, Bl + 1024);                                               \
        GLDS(Bp + 48 * KDIM, Bl + 1536);                                               \
        Ap += 32;                                                                      \
        Bp += 32;                                                                      \
    } while (0)

#define PCOMPUTE(bufidx)                                                               \
    do {                                                                               \
        bf16x8 af[4], bfr[4];                                                          \
        _Pragma("unroll") for (int mi = 0; mi < 4; mi++) af[mi] =                      \
            *(const bf16x8*)&SH[(bufidx)*2048 + (mi * 16 + llo) * 32 + gsw];           \
        _Pragma("unroll") for (int ni = 0; ni < 4; ni++) bfr[ni] =                     \
            *(const bf16x8*)&SH[6144 + (bufidx)*8192 +                                 \
                                (wid * 64 + ni * 16 + llo) * 32 + gsw];                \
        _Pragma("unroll") for (int mi = 0; mi < 4; mi++)                               \
            _Pragma("unroll") for (int ni = 0; ni < 4; ni++) acc[mi][ni] =             \
                __builtin_amdgcn_mfma_f32_16x16x32_bf16(bfr[ni], af[mi],               \
                                                        acc[mi][ni], 0, 0, 0);         \
    } while (0)

#define PWAITBAR(N)                                                                    \
    asm volatile("s_waitcnt vmcnt(" #N ")" ::: "memory");                              \
    __builtin_amdgcn_s_barrier();                                                      \
    __builtin_amdgcn_sched_barrier(0)

    PSTAGE(0);
    PSTAGE(1);
    PSTAGE(2);
    int buf = 0;
    for (int i = 0; i + 3 < 8; ++i) {
        PWAITBAR(10);
        PCOMPUTE(buf);
        asm volatile("s_waitcnt lgkmcnt(0)" ::: "memory");
        __builtin_amdgcn_s_barrier();
        __builtin_amdgcn_sched_barrier(0);
        PSTAGE(buf);
        buf = (buf == 2) ? 0 : buf + 1;
    }
    PWAITBAR(10);
    PCOMPUTE(buf);
    buf = (buf == 2) ? 0 : buf + 1;
    PWAITBAR(5);
    PCOMPUTE(buf);
    buf = (buf == 2) ? 0 : buf + 1;
    PWAITBAR(0);
    PCOMPUTE(buf);

#undef PSTAGE
#undef PCOMPUTE
#undef PWAITBAR

    __syncthreads();

    char* shb = (char*)SH;
#pragma unroll
    for (int ni = 0; ni < 4; ni++) {
        const int col0 = wid * 64 + ni * 16 + lhi * 4;
        const float4 b4 = *(const float4*)&bias[col0];
#pragma unroll
        for (int mi = 0; mi < 4; mi++) {
            const int ltok = mi * 16 + llo;
            float4 o = {acc[mi][ni][0] + b4.x, acc[mi][ni][1] + b4.y,
                        acc[mi][ni][2] + b4.z, acc[mi][ni][3] + b4.w};
            const int u2 = (col0 >> 2) ^ (ltok & 15);
            *(float4*)(shb + ltok * 1024 + u2 * 16) = o;
        }
    }
    __syncthreads();

    const float4 gg = *(const float4*)&g2[lane * 4];
    const float4 bb4 = *(const float4*)&b2[lane * 4];
#pragma unroll
    for (int rnd = 0; rnd < 16; rnd++) {
        const int t = rnd * 4 + wid;
        const int u2 = lane ^ (t & 15);
        float4 v = *(const float4*)(shb + t * 1024 + u2 * 16);
        const int grow = bm * 64 + t;
        int w = grow >> 6, n = grow & 63;
        int b = w >> 6, nw = w & 63;
        int rr = ((nw >> 3) * 8 + (n >> 3) + 4) & 63;
        int cc = ((nw & 7) * 8 + (n & 7) + 4) & 63;
        const size_t rowbase = ((size_t)b * 4096 + rr * 64 + cc) * 256;
        float4 rs = *(const float4*)&resid[rowbase + lane * 4];
        float4 o = {rs.x + v.x, rs.y + v.y, rs.z + v.z, rs.w + v.w};
        bf16x4 bo = {(bf16)o.x, (bf16)o.y, (bf16)o.z, (bf16)o.w};
        *(bf16x4*)&baseb[rowbase + lane * 4] = bo;
        float s = o.x + o.y + o.z + o.w;
        float sq = o.x * o.x + o.y * o.y + o.z * o.z + o.w * o.w;
#pragma unroll
        for (int off = 1; off < 64; off <<= 1) {
            s += __shfl_xor(s, off);
            sq += __shfl_xor(sq, off);
        }
        float mean = s * (1.0f / 256.0f);
        float var = sq * (1.0f / 256.0f) - mean * mean;
        float rstd = rsqrtf(var + 1e-5f);
        bf16x4 ho;
        ho[0] = (bf16)((o.x - mean) * rstd * gg.x + bb4.x);
        ho[1] = (bf16)((o.y - mean) * rstd * gg.y + bb4.y);
        ho[2] = (bf16)((o.z - mean) * rstd * gg.z + bb4.z);
        ho[3] = (bf16)((o.w - mean) * rstd * gg.w + bb4.w);
        *(bf16x4*)&hb[rowbase + lane * 4] = ho;
    }
}

// ---------------- windowed attention ----------------
__device__ __forceinline__ int regid3(int p) { return p < 56 ? 0 : (p < 60 ? 1 : 2); }

__global__ __launch_bounds__(256) void attn_k(const bf16* __restrict__ qkv,
                                              const float* __restrict__ rpb,
                                              bf16* __restrict__ aout) {
    __shared__ __align__(16) bf16 Pl[4][64 * 80];
    const int wid = threadIdx.x >> 6, lane = threadIdx.x & 63;
    const int lhi = lane >> 4, llo = lane & 15;
    const int wh = blockIdx.x * 4 + wid;
    const int w = wh >> 3, h = wh & 7;
    const bf16* base = qkv + (size_t)w * (64 * 768);

    bf16x8 qf[4], kf[4];
#pragma unroll
    for (int i = 0; i < 4; i++)
        qf[i] = *(const bf16x8*)(base + (i * 16 + llo) * 768 + h * 32 + lhi * 8);
#pragma unroll
    for (int i = 0; i < 4; i++)
        kf[i] = *(const bf16x8*)(base + (i * 16 + llo) * 768 + 256 + h * 32 + lhi * 8);
    f32x4 s[4][4];
#pragma unroll
    for (int mi = 0; mi < 4; mi++)
#pragma unroll
        for (int ni = 0; ni < 4; ni++) {
            s[mi][ni] = f32x4{0.f, 0.f, 0.f, 0.f};
            s[mi][ni] =
                __builtin_amdgcn_mfma_f32_16x16x32_bf16(qf[mi], kf[ni], s[mi][ni], 0, 0, 0);
        }

    const int nw = w & 63;
    const int pr0 = (nw >> 3) * 8, pc0 = (nw & 7) * 8;
    int creg[4];
#pragma unroll
    for (int ni = 0; ni < 4; ni++) {
        int m = ni * 16 + llo;
        creg[ni] = regid3(pr0 + (m >> 3)) * 3 + regid3(pc0 + (m & 7));
    }
    float rmax[4][4], rsum[4][4];
#pragma unroll
    for (int mi = 0; mi < 4; mi++)
#pragma unroll
        for (int r = 0; r < 4; r++) {
            int n = mi * 16 + lhi * 4 + r;
            int rreg = regid3(pr0 + (n >> 3)) * 3 + regid3(pc0 + (n & 7));
            float mx = -1e30f;
#pragma unroll
            for (int ni = 0; ni < 4; ni++) {
                int m = ni * 16 + llo;
                float sv = s[mi][ni][r] * 0.17677669529663687f + rpb[(h * 64 + n) * 64 + m] +
                           (rreg == creg[ni] ? 0.0f : -100.0f);
                s[mi][ni][r] = sv;
                mx = fmaxf(mx, sv);
            }
            rmax[mi][r] = mx;
        }
#pragma unroll
    for (int off = 1; off < 16; off <<= 1)
#pragma unroll
        for (int mi = 0; mi < 4; mi++)
#pragma unroll
            for (int r = 0; r < 4; r++)
                rmax[mi][r] = fmaxf(rmax[mi][r], __shfl_xor(rmax[mi][r], off));
#pragma unroll
    for (int mi = 0; mi < 4; mi++)
#pragma unroll
        for (int r = 0; r < 4; r++) {
            float a = 0.f;
#pragma unroll
            for (int ni = 0; ni < 4; ni++) {
                float p = __expf(s[mi][ni][r] - rmax[mi][r]);
                s[mi][ni][r] = p;
                a += p;
            }
            rsum[mi][r] = a;
        }
#pragma unroll
    for (int off = 1; off < 16; off <<= 1)
#pragma unroll
        for (int mi = 0; mi < 4; mi++)
#pragma unroll
            for (int r = 0; r < 4; r++) rsum[mi][r] += __shfl_xor(rsum[mi][r], off);

    bf16* P = Pl[wid];
#pragma unroll
    for (int mi = 0; mi < 4; mi++)
#pragma unroll
        for (int r = 0; r < 4; r++) {
            float rinv = 1.0f / rsum[mi][r];
            int row = mi * 16 + lhi * 4 + r;
#pragma unroll
            for (int ni = 0; ni < 4; ni++)
                P[row * 80 + ni * 16 + llo] = (bf16)(s[mi][ni][r] * rinv);
        }

    f32x4 o[4][2];
#pragma unroll
    for (int mi = 0; mi < 4; mi++)
#pragma unroll
        for (int ni = 0; ni < 2; ni++) o[mi][ni] = f32x4{0.f, 0.f, 0.f, 0.f};
#pragma unroll
    for (int kc = 0; kc < 2; kc++) {
        bf16x8 pf[4], vf[2];
#pragma unroll
        for (int mi = 0; mi < 4; mi++)
            pf[mi] = *(const bf16x8*)(P + (mi * 16 + llo) * 80 + kc * 32 + lhi * 8);
#pragma unroll
        for (int ni = 0; ni < 2; ni++)
#pragma unroll
            for (int j = 0; j < 8; j++)
                vf[ni][j] = base[(kc * 32 + lhi * 8 + j) * 768 + 512 + h * 32 + ni * 16 + llo];
#pragma unroll
        for (int mi = 0; mi < 4; mi++)
#pragma unroll
            for (int ni = 0; ni < 2; ni++)
                o[mi][ni] =
                    __builtin_amdgcn_mfma_f32_16x16x32_bf16(pf[mi], vf[ni], o[mi][ni], 0, 0, 0);
    }
#pragma unroll
    for (int mi = 0; mi < 4; mi++)
#pragma unroll
        for (int ni = 0; ni < 2; ni++)
#pragma unroll
            for (int r = 0; r < 4; r++) {
                int row = mi * 16 + lhi * 4 + r;
                aout[(size_t)(w * 64 + row) * 256 + h * 32 + ni * 16 + llo] =
                    (bf16)o[mi][ni][r];
            }
}

// ---------------- launcher (R13: 4 chunks x 8 images) ----------------
extern "C" void kernel_launch(void* const* d_in, const int* in_sizes, int n_in,
                              void* d_out, int out_size, void* d_ws, size_t ws_size,
                              hipStream_t stream) {
    const float* x      = (const float*)d_in[0];
    const float* n1g    = (const float*)d_in[1];
    const float* n1b    = (const float*)d_in[2];
    const float* qkv_w  = (const float*)d_in[3];
    const float* qkv_b  = (const float*)d_in[4];
    const float* proj_w = (const float*)d_in[5];
    const float* proj_b = (const float*)d_in[6];
    const float* btab   = (const float*)d_in[7];
    const float* n2g    = (const float*)d_in[8];
    const float* n2b    = (const float*)d_in[9];
    const float* fc1_w  = (const float*)d_in[10];
    const float* fc1_b  = (const float*)d_in[11];
    const float* fc2_w  = (const float*)d_in[12];
    const float* fc2_b  = (const float*)d_in[13];
    float* out = (float*)d_out;
    char* ws = (char*)d_ws;

    constexpr size_t MB = 1048576ull;
    bf16* XWc   = (bf16*)(ws);              // 16.8MB
    bf16* QKVc  = (bf16*)(ws + 17 * MB);    // 50.4MB
    bf16* ATTNc = (bf16*)(ws + 68 * MB);    // 16.8MB
    bf16* BASEc = (bf16*)(ws + 85 * MB);    // 16.8MB
    bf16* Hbc   = (bf16*)(ws + 102 * MB);   // 16.8MB
    bf16* Gc    = (bf16*)(ws + 119 * MB);   // 67.1MB
    bf16* WQ    = (bf16*)(ws + 187 * MB);
    bf16* WP    = (bf16*)(ws + 187 * MB + 393216);
    bf16* W1    = (bf16*)(ws + 187 * MB + 524288);
    bf16* W2    = (bf16*)(ws + 187 * MB + 1048576);
    float* RPB  = (float*)(ws + 187 * MB + 1572864);

    dim3 blk(256);
    prep_all<<<3200, blk, 0, stream>>>(qkv_w, proj_w, fc1_w, fc2_w, btab,
                                       WQ, WP, W1, W2, RPB);

    for (int c = 0; c < 4; ++c) {
        const size_t xo = (size_t)c * 32768 * 256;
        // LN1 + shift + partition (chunk-local)
        ln_k<<<8192, blk, 0, stream>>>(x + xo, n1g, n1b, XWc);
        // QKV
        gemm_k<768, 256, 0><<<1536, blk, 0, stream>>>(XWc, WQ, qkv_b, QKVc,
                                                      nullptr, nullptr);
        // attention (512 windows x 8 heads / 4 waves)
        attn_k<<<1024, blk, 0, stream>>>(QKVc, RPB, ATTNc);
        // proj + residual + reverse/unshift + LN2 -> baseb, Hb
        proj_ln_k<<<512, blk, 0, stream>>>(ATTNc, WP, proj_b, x + xo, BASEc,
                                           n2g, n2b, Hbc);
        // FC1 + GELU
        gemm_k<1024, 256, 2><<<2048, blk, 0, stream>>>(Hbc, W1, fc1_b, Gc,
                                                       nullptr, nullptr);
        // FC2 + bias + base -> out (single write)
        gemm_k<256, 1024, 3><<<512, blk, 0, stream>>>(Gc, W2, fc2_b, nullptr,
                                                      out + xo, BASEc);
    }
}